// Round 4
// baseline (191.783 us; speedup 1.0000x reference)
//
#include <hip/hip_runtime.h>
#include <math.h>

// ---------------------------------------------------------------------------
// EntRNN R13: single fused kernel WITHOUT cooperative launch (R12's
// hipLaunchCooperativeKernel silently failed -> zero output). Grid-wide
// dependency is handled by per-chunk publish flags: each block writes its
// chunk aggregates (Ap,Hp), fences (agent scope: wbl2), release-stores
// flags[g]=1; consumers spin on acquire loads of their <=63 predecessor
// flags, fence (inv), then walk the f32 aggregates. 512 blocks x 64 KiB LDS
// x launch_bounds(256,2) = exactly 2 blocks/CU -> all co-resident; waits
// only target lower block ids (in-order dispatch) -> no deadlock.
// Pipeline per block: R10's proven K-loop (48 KiB LDS: A xor-swizzled + W
// slice, reg double-buffer) -> activations for all 64 rows into 64 KiB LDS
// -> in-LDS local scan (h,P f16x2) -> publish aggregates -> spin -> carry
// walk -> apply + stream f32 out. No 32 MiB HP round-trip, no scan_mid /
// final_k kernels. B=8, T=4096, D=256.
// ---------------------------------------------------------------------------

typedef _Float16 f16x8 __attribute__((ext_vector_type(8)));
typedef float f32x4 __attribute__((ext_vector_type(4)));
typedef float f32x16 __attribute__((ext_vector_type(16)));
typedef unsigned int u32x4 __attribute__((ext_vector_type(4)));

constexpr int B_ = 8, T_ = 4096, D_ = 256, K_ = 256;
constexpr int M_ = B_ * T_;          // 32768 rows
constexpr int CHUNK = 64;            // rows per block == scan chunk
constexpr int NCH = T_ / CHUNK;      // 64 chunks per sequence
constexpr int NBLK = M_ / CHUNK;     // 512 blocks
constexpr int SLICE_EL = 8192;       // W slice stride: 1024 chunks * 8 f16

struct alignas(4) XF { _Float16 x, f; };
struct alignas(4) HP2 { _Float16 h, p; };
union UHP { unsigned int u; HP2 hp; XF xf; };

__device__ __forceinline__ float fexp2(float a) { return __builtin_amdgcn_exp2f(a); }
__device__ __forceinline__ float frcp(float a) { return __builtin_amdgcn_rcpf(a); }
constexpr float L2E = 1.4426950408889634f;

__device__ __forceinline__ float fast_sigmoid(float z) {
  return frcp(1.f + fexp2(-z * L2E));
}
__device__ __forceinline__ float fast_tanh(float z) {
  const float t = fexp2(-2.f * L2E * fabsf(z));
  return copysignf((1.f - t) * frcp(1.f + t), z);
}

// ---- K0: repack W fp32 -> f16 and zero the publish flags. ----------------
// Chunk id t = kk2*1024 + (mat*2+kc)*256 + n, chunk = W[n][kk2*16+kc*8 ..+8).
__global__ __launch_bounds__(256) void wconv(const float* __restrict__ Win,
                                             const float* __restrict__ Wf,
                                             _Float16* __restrict__ Wh2,
                                             int* __restrict__ flags) {
  const int t = blockIdx.x * 256 + threadIdx.x;
  if (t < NBLK) flags[t] = 0;
  const int n = t & 255;
  const int kc = (t >> 8) & 1;
  const int mat = (t >> 9) & 1;
  const int kk2 = t >> 10;
  const float* s = (mat ? Wf : Win) + (size_t)n * K_ + kk2 * 16 + kc * 8;
  f32x4 a = *(const f32x4*)s;
  f32x4 b = *(const f32x4*)(s + 4);
  f16x8 o;
  o[0] = (_Float16)a[0]; o[1] = (_Float16)a[1];
  o[2] = (_Float16)a[2]; o[3] = (_Float16)a[3];
  o[4] = (_Float16)b[0]; o[5] = (_Float16)b[1];
  o[6] = (_Float16)b[2]; o[7] = (_Float16)b[3];
  *(f16x8*)(Wh2 + (size_t)t * 8) = o;
}

// ---- K1: GEMM + activations + local scan + flag-sync + carry + output ----
__global__ __launch_bounds__(256, 2) void fused(
    const float* __restrict__ A, const _Float16* __restrict__ Wh2,
    const float* __restrict__ bin, const float* __restrict__ bfv,
    const float* __restrict__ mask, float* __restrict__ Ap,
    float* __restrict__ Hp, int* __restrict__ flags,
    float* __restrict__ out) {
  __shared__ __align__(16) char smem[65536];
  char* ldsA = smem;            // 32 KiB during GEMM: [m(64)][swz(32)] 16B
  char* ldsW = smem + 32768;    // 16 KiB W slice during GEMM
  // after GEMM: smem[0:65536) = 64 rows x 256 cols of XF/HP2 (4B each)

  const int tid = threadIdx.x;
  const int w = tid >> 6, lane = tid & 63;
  const int mw = w >> 1, nw = w & 1;
  const int nl = lane & 31, kh = lane >> 5;
  const int ml = mw * 32 + nl;
  const int g = blockIdx.x;
  const int row0 = g * CHUNK;

  f32x16 acc[2][4];
#pragma unroll
  for (int mat = 0; mat < 2; ++mat)
#pragma unroll
    for (int nt = 0; nt < 4; ++nt) acc[mat][nt] = (f32x16)(0.f);

  // ---- stage ALL of A (64 x 256) fp32->f16, xor-swizzled ----
  {
    const int am = tid >> 2;
    const int ak4 = (tid & 3) * 8;
    const float* agp = A + (size_t)(row0 + am) * K_ + ak4 * 8;
#pragma unroll
    for (int j = 0; j < 8; ++j) {
      const int kcg = ak4 + j;
      f32x4 lo = *(const f32x4*)(agp + j * 8);
      f32x4 hi = *(const f32x4*)(agp + j * 8 + 4);
      f16x8 t;
      t[0] = (_Float16)lo[0]; t[1] = (_Float16)lo[1];
      t[2] = (_Float16)lo[2]; t[3] = (_Float16)lo[3];
      t[4] = (_Float16)hi[0]; t[5] = (_Float16)hi[1];
      t[6] = (_Float16)hi[2]; t[7] = (_Float16)hi[3];
      *(f16x8*)(ldsA + am * 512 + ((kcg ^ (am & 31)) << 4)) = t;
    }
  }

  // ---- prologue: W slice kk2=0 into regs (4 x b128) ----
  f16x8 wreg[4];
#pragma unroll
  for (int j = 0; j < 4; ++j)
    wreg[j] = *(const f16x8*)(Wh2 + (size_t)(j * 256 + tid) * 8);
  __syncthreads();

  // ---- K-loop: 16 slices of K=16 (R10/R6 pattern, LDS W double-buffer) ----
  for (int kk2 = 0; kk2 < 16; ++kk2) {
#pragma unroll
    for (int j = 0; j < 4; ++j)
      *(f16x8*)(ldsW + (size_t)(j * 256 + tid) * 16) = wreg[j];
    if (kk2 < 15) {
#pragma unroll
      for (int j = 0; j < 4; ++j)
        wreg[j] = *(const f16x8*)(Wh2 + (size_t)(kk2 + 1) * SLICE_EL +
                                  (size_t)(j * 256 + tid) * 8);
    }
    __syncthreads();
    f16x8 afr;
    {
      const int kcg = kk2 * 2 + kh;
      afr = *(const f16x8*)(ldsA + ml * 512 + ((kcg ^ (ml & 31)) << 4));
    }
#pragma unroll
    for (int mat = 0; mat < 2; ++mat)
#pragma unroll
      for (int nt = 0; nt < 4; ++nt) {
        const int n = nw * 128 + nt * 32 + nl;
        f16x8 bfr = *(const f16x8*)(ldsW + (size_t)((mat * 2 + kh) * 256 + n) * 16);
        acc[mat][nt] = __builtin_amdgcn_mfma_f32_32x32x16_f16(
            afr, bfr, acc[mat][nt], 0, 0, 0);
      }
    __syncthreads();
  }

  // ---- epilogue: activations for ALL 64 rows into 64 KiB LDS ----
  float bx[4], bf[4];
#pragma unroll
  for (int nt = 0; nt < 4; ++nt) {
    const int col = nw * 128 + nt * 32 + nl;
    bx[nt] = bin[col];
    bf[nt] = bfv[col];
  }
  float madd[16];
#pragma unroll
  for (int reg = 0; reg < 16; ++reg) {
    const int rl = mw * 32 + (reg & 3) + 8 * (reg >> 2) + 4 * kh;
    madd[reg] = 10000.f * mask[row0 + rl];
  }

#pragma unroll
  for (int nt = 0; nt < 4; ++nt) {
    const int col = nw * 128 + nt * 32 + nl;
#pragma unroll
    for (int reg = 0; reg < 16; ++reg) {
      const int rloc = mw * 32 + (reg & 3) + 8 * (reg >> 2) + 4 * kh;  // 0..63
      const float zx = acc[0][nt][reg] + bx[nt];
      const float zf = acc[1][nt][reg] + bf[nt] + madd[reg];
      XF v;
      v.x = (_Float16)fast_tanh(zx);
      v.f = (_Float16)fast_sigmoid(zf);
      *(XF*)(smem + ((size_t)rloc * D_ + col) * 4) = v;
    }
  }
  __syncthreads();

  // ---- local scan: 64 timesteps in place (XF -> HP2) ----
  const int d = tid;
  float hrun = 0.f, Prun = 1.f;
#pragma unroll 8
  for (int t = 0; t < 64; ++t) {
    char* slot = smem + ((size_t)t * D_ + d) * 4;
    const XF v = *(const XF*)slot;
    const float f = (float)v.f;
    const float a = 1.f - f;
    hrun = f * (float)v.x + a * hrun;
    Prun *= a;
    HP2 o;
    o.h = (_Float16)hrun;
    o.p = (_Float16)Prun;
    *(HP2*)slot = o;
  }
  // chunk aggregates to global (f32)
  Ap[(size_t)g * D_ + d] = Prun;
  Hp[(size_t)g * D_ + d] = hrun;

  // ---- publish: all stores drained -> L2 writeback -> release flag ----
  __syncthreads();            // drains vmcnt for all 256 threads' stores
  __threadfence();            // agent fence: buffer_wbl2 (publish our L2)
  if (tid == 0)
    __hip_atomic_store(flags + g, 1, __ATOMIC_RELEASE,
                       __HIP_MEMORY_SCOPE_AGENT);

  // ---- wait for the c predecessor chunks of this sequence ----
  const int c = g & (NCH - 1);          // chunk index within sequence
  const int g0 = g & ~(NCH - 1);        // first block of this sequence
  if (tid < c) {
    while (__hip_atomic_load(flags + g0 + tid, __ATOMIC_ACQUIRE,
                             __HIP_MEMORY_SCOPE_AGENT) == 0)
      __builtin_amdgcn_s_sleep(2);
  }
  __syncthreads();
  __threadfence();            // acquire side: invalidate stale L1/L2 lines

  // ---- carry walk: prefix over chunks [0, c) of this sequence, f32x4 ----
  const int wv = tid >> 6;
  const int d0 = (tid & 63) * 4;
  const size_t seqbase = (size_t)g0 * D_ + d0;
  f32x4 h0 = (f32x4)(0.f);
#pragma unroll 4
  for (int j = 0; j < c; ++j) {
    const f32x4 a4 = *(const f32x4*)(Ap + seqbase + (size_t)j * D_);
    const f32x4 hh = *(const f32x4*)(Hp + seqbase + (size_t)j * D_);
    h0 = hh + a4 * h0;
  }

  // ---- apply carry + stream output (f32x4 coalesced) ----
#pragma unroll 4
  for (int tt = 0; tt < 16; ++tt) {
    const int t = wv * 16 + tt;
    const u32x4 u = *(const u32x4*)(smem + ((size_t)t * D_ + d0) * 4);
    f32x4 o;
#pragma unroll
    for (int i = 0; i < 4; ++i) {
      UHP q; q.u = u[i];
      o[i] = (float)q.hp.h + (float)q.hp.p * h0[i];
    }
    *(f32x4*)(out + ((size_t)(row0 + t)) * D_ + d0) = o;
  }
}

// ---------------------------------------------------------------------------
extern "C" void kernel_launch(void* const* d_in, const int* in_sizes, int n_in,
                              void* d_out, int out_size, void* d_ws, size_t ws_size,
                              hipStream_t stream) {
  const float* inputs = (const float*)d_in[0];
  const float* mask   = (const float*)d_in[1];
  const float* W_in   = (const float*)d_in[2];
  const float* b_in   = (const float*)d_in[3];
  const float* W_f    = (const float*)d_in[4];
  const float* b_f    = (const float*)d_in[5];
  float* out = (float*)d_out;
  char* ws = (char*)d_ws;

  constexpr size_t WSZ = (size_t)2 * 256 * 256 * 2;               // 256 KiB
  constexpr size_t SUM = (size_t)NBLK * D_ * sizeof(float);       // 512 KiB

  _Float16* Wh2 = (_Float16*)ws;
  float* Ap = (float*)(ws + WSZ);
  float* Hp = (float*)(ws + WSZ + SUM);
  int* flags = (int*)(ws + WSZ + 2 * SUM);

  wconv<<<64, 256, 0, stream>>>(W_in, W_f, Wh2, flags);
  fused<<<NBLK, 256, 0, stream>>>(inputs, Wh2, b_in, b_f, mask, Ap, Hp,
                                  flags, out);
}

// Round 7
// 140.723 us; speedup vs baseline: 1.3628x; 1.3628x over previous
//
#include <hip/hip_runtime.h>
#include <math.h>

// ---------------------------------------------------------------------------
// EntRNN R14c: resubmit of R14 (Rounds 5 and 6 never acquired a GPU). Split
// kernels (R13's in-kernel flag/fence sync cost +60us > tail savings; kernel
// boundaries are the cheap device fence). Changes vs R10 baseline:
//  * CHUNK 64 -> 32: block = 32 rows x (2 mats x 256 cols), acc = 4 x f32x16
//    (64 regs), LDS = 32 KiB (16K A + 16K W slice; epilogue reuses as 32K XF
//    stage) -> 1024 blocks, 4 blocks/CU co-resident = 16 waves/CU (2x R10's
//    latency hiding, the counters' only consistent complaint).
//  * Wave owns 64 cols of BOTH matrices (acc[2][2]) so the interleaved XF
//    epilogue write stays wave-local.
//  * scan_mid + hs deleted: the apply kernel walks its own <=127-chunk
//    prefix of the f32 Ap/Hp aggregates (L2-resident, 2 KB/chunk).
// B=8, T=4096, D=256.
// ---------------------------------------------------------------------------

typedef _Float16 f16x8 __attribute__((ext_vector_type(8)));
typedef float f32x4 __attribute__((ext_vector_type(4)));
typedef float f32x16 __attribute__((ext_vector_type(16)));
typedef unsigned int u32x4 __attribute__((ext_vector_type(4)));

constexpr int B_ = 8, T_ = 4096, D_ = 256, K_ = 256;
constexpr int M_ = B_ * T_;          // 32768 rows
constexpr int CHUNK = 32;            // rows per gemm block == scan chunk
constexpr int NCH = T_ / CHUNK;      // 128 chunks per sequence
constexpr int NBLK = M_ / CHUNK;     // 1024 gemm blocks
constexpr int SLICE_EL = 8192;       // W slice stride: 16 k x 512 cols f16

struct alignas(4) XF { _Float16 x, f; };
struct alignas(4) HP2 { _Float16 h, p; };
union UHP { unsigned int u; HP2 hp; XF xf; };

__device__ __forceinline__ float fexp2(float a) { return __builtin_amdgcn_exp2f(a); }
__device__ __forceinline__ float frcp(float a) { return __builtin_amdgcn_rcpf(a); }
constexpr float L2E = 1.4426950408889634f;

__device__ __forceinline__ float fast_sigmoid(float z) {
  return frcp(1.f + fexp2(-z * L2E));
}
__device__ __forceinline__ float fast_tanh(float z) {
  const float t = fexp2(-2.f * L2E * fabsf(z));
  return copysignf((1.f - t) * frcp(1.f + t), z);
}

// ---- K0: repack W fp32 -> f16. Chunk id t = kk2*1024 + (mat*2+kc)*256 + n,
// chunk = W[n][kk2*16 + kc*8 .. +8). 16384 chunks of 8 f16.
__global__ __launch_bounds__(256) void wconv(const float* __restrict__ Win,
                                             const float* __restrict__ Wf,
                                             _Float16* __restrict__ Wh2) {
  const int t = blockIdx.x * 256 + threadIdx.x;
  const int n = t & 255;
  const int kc = (t >> 8) & 1;
  const int mat = (t >> 9) & 1;
  const int kk2 = t >> 10;
  const float* s = (mat ? Wf : Win) + (size_t)n * K_ + kk2 * 16 + kc * 8;
  f32x4 a = *(const f32x4*)s;
  f32x4 b = *(const f32x4*)(s + 4);
  f16x8 o;
  o[0] = (_Float16)a[0]; o[1] = (_Float16)a[1];
  o[2] = (_Float16)a[2]; o[3] = (_Float16)a[3];
  o[4] = (_Float16)b[0]; o[5] = (_Float16)b[1];
  o[6] = (_Float16)b[2]; o[7] = (_Float16)b[3];
  *(f16x8*)(Wh2 + (size_t)t * 8) = o;
}

// ---- K1: GEMM (32-row tile) + activations + local scan -> HP --------------
// 1024 blocks x 256 thr, 32 KiB LDS -> 4 blocks/CU (VGPR-capped via
// launch_bounds(256,4)). Wave w owns cols [w*64, w*64+64) of BOTH matrices.
__global__ __launch_bounds__(256, 4) void gemm_hp(
    const float* __restrict__ A, const _Float16* __restrict__ Wh2,
    const float* __restrict__ bin, const float* __restrict__ bfv,
    const float* __restrict__ mask, unsigned int* __restrict__ HPout,
    float* __restrict__ Ap, float* __restrict__ Hp) {
  __shared__ __align__(16) char smem[32768];
  char* ldsA = smem;            // 16 KiB: [m(32)][swz(32)] 16B, swz = kcg^m
  char* ldsW = smem + 16384;    // 16 KiB slice: [(mat*2+kc)*256 + n] 16B
  // epilogue: smem[0:32768) = 32 rows x 256 cols of XF/HP2 (4B each)

  const int tid = threadIdx.x;
  const int w = tid >> 6, lane = tid & 63;
  const int nl = lane & 31, kh = lane >> 5;
  const int g = blockIdx.x;
  const int row0 = g * CHUNK;

  f32x16 acc[2][2];
#pragma unroll
  for (int mat = 0; mat < 2; ++mat)
#pragma unroll
    for (int nt = 0; nt < 2; ++nt) acc[mat][nt] = (f32x16)(0.f);

  // ---- stage ALL of A (32 x 256) fp32->f16, xor-swizzled ----
  {
    const int am = tid >> 3;                 // row 0..31 (8 thr/row)
    const int ak4 = (tid & 7) * 4;           // 16B-chunk base within row
    const float* agp = A + (size_t)(row0 + am) * K_ + (tid & 7) * 32;
#pragma unroll
    for (int j = 0; j < 4; ++j) {
      const int kcg = ak4 + j;
      f32x4 lo = *(const f32x4*)(agp + j * 8);
      f32x4 hi = *(const f32x4*)(agp + j * 8 + 4);
      f16x8 t;
      t[0] = (_Float16)lo[0]; t[1] = (_Float16)lo[1];
      t[2] = (_Float16)lo[2]; t[3] = (_Float16)lo[3];
      t[4] = (_Float16)hi[0]; t[5] = (_Float16)hi[1];
      t[6] = (_Float16)hi[2]; t[7] = (_Float16)hi[3];
      *(f16x8*)(ldsA + am * 512 + ((kcg ^ am) << 4)) = t;
    }
  }

  // ---- prologue: W slice kk2=0 into regs (4 x b128) ----
  f16x8 wreg[4];
#pragma unroll
  for (int j = 0; j < 4; ++j)
    wreg[j] = *(const f16x8*)(Wh2 + (size_t)(j * 256 + tid) * 8);
  __syncthreads();

  // ---- K-loop: 16 slices of K=16 (reg-prefetch double buffer) ----
  for (int kk2 = 0; kk2 < 16; ++kk2) {
#pragma unroll
    for (int j = 0; j < 4; ++j)
      *(f16x8*)(ldsW + (size_t)(j * 256 + tid) * 16) = wreg[j];
    if (kk2 < 15) {
#pragma unroll
      for (int j = 0; j < 4; ++j)
        wreg[j] = *(const f16x8*)(Wh2 + (size_t)(kk2 + 1) * SLICE_EL +
                                  (size_t)(j * 256 + tid) * 8);
    }
    __syncthreads();
    f16x8 afr;
    {
      const int kcg = kk2 * 2 + kh;
      afr = *(const f16x8*)(ldsA + nl * 512 + ((kcg ^ nl) << 4));
    }
#pragma unroll
    for (int mat = 0; mat < 2; ++mat)
#pragma unroll
      for (int nt = 0; nt < 2; ++nt) {
        const int n = w * 64 + nt * 32 + nl;
        f16x8 bfr = *(const f16x8*)(ldsW + (size_t)((mat * 2 + kh) * 256 + n) * 16);
        acc[mat][nt] = __builtin_amdgcn_mfma_f32_32x32x16_f16(
            afr, bfr, acc[mat][nt], 0, 0, 0);
      }
    __syncthreads();
  }

  // ---- epilogue: activations for all 32 rows into 32 KiB LDS ----
  float bx[2], bf[2];
#pragma unroll
  for (int nt = 0; nt < 2; ++nt) {
    const int col = w * 64 + nt * 32 + nl;
    bx[nt] = bin[col];
    bf[nt] = bfv[col];
  }
  float madd[16];
#pragma unroll
  for (int reg = 0; reg < 16; ++reg) {
    const int rl = (reg & 3) + 8 * (reg >> 2) + 4 * kh;   // 0..31
    madd[reg] = 10000.f * mask[row0 + rl];
  }

#pragma unroll
  for (int nt = 0; nt < 2; ++nt) {
    const int col = w * 64 + nt * 32 + nl;
#pragma unroll
    for (int reg = 0; reg < 16; ++reg) {
      const int rloc = (reg & 3) + 8 * (reg >> 2) + 4 * kh;  // 0..31
      const float zx = acc[0][nt][reg] + bx[nt];
      const float zf = acc[1][nt][reg] + bf[nt] + madd[reg];
      XF v;
      v.x = (_Float16)fast_tanh(zx);
      v.f = (_Float16)fast_sigmoid(zf);
      *(XF*)(smem + ((size_t)rloc * D_ + col) * 4) = v;
    }
  }
  __syncthreads();

  // ---- local scan: 32 timesteps in place (XF -> HP2) ----
  const int d = tid;
  float hrun = 0.f, Prun = 1.f;
#pragma unroll 8
  for (int t = 0; t < 32; ++t) {
    char* slot = smem + ((size_t)t * D_ + d) * 4;
    const XF v = *(const XF*)slot;
    const float f = (float)v.f;
    const float a = 1.f - f;
    hrun = f * (float)v.x + a * hrun;
    Prun *= a;
    HP2 o;
    o.h = (_Float16)hrun;
    o.p = (_Float16)Prun;
    *(HP2*)slot = o;
  }
  __syncthreads();

  // ---- bulk-coalesced b128 store of the 32-row HP stage (32 KiB) ----
#pragma unroll
  for (int j = 0; j < 8; ++j) {
    const int c = j * 256 + tid;              // 16B chunk id in [0,2048)
    u32x4 vv = *(const u32x4*)(smem + (size_t)c * 16);
    *(u32x4*)(HPout + (size_t)g * 8192 + (size_t)c * 4) = vv;
  }

  Ap[(size_t)g * D_ + d] = Prun;
  Hp[(size_t)g * D_ + d] = hrun;
}

// ---- K2: prefix walk over chunk aggregates + apply + stream out -----------
// 1024 blocks x 256 thr, no LDS. Kernel boundary provides device coherence.
__global__ __launch_bounds__(256) void final_k(const unsigned int* __restrict__ HP,
                                               const float* __restrict__ Ap,
                                               const float* __restrict__ Hp,
                                               float* __restrict__ out) {
  const int g = blockIdx.x;
  const int c = g & (NCH - 1);          // chunk index within sequence
  const int g0 = g & ~(NCH - 1);        // first chunk-block of this sequence
  const int wv = threadIdx.x >> 6;
  const int d0 = (threadIdx.x & 63) * 4;

  // carry INTO chunk c: h0 = fold over chunks [0, c)
  const size_t seqbase = (size_t)g0 * D_ + d0;
  f32x4 h0 = (f32x4)(0.f);
#pragma unroll 4
  for (int j = 0; j < c; ++j) {
    const f32x4 a4 = *(const f32x4*)(Ap + seqbase + (size_t)j * D_);
    const f32x4 hh = *(const f32x4*)(Hp + seqbase + (size_t)j * D_);
    h0 = hh + a4 * h0;
  }

#pragma unroll 4
  for (int tt = 0; tt < 8; ++tt) {
    const int t = wv * 8 + tt;
    const size_t idx = ((size_t)g * CHUNK + t) * D_ + d0;
    u32x4 u = *(const u32x4*)(HP + idx);
    f32x4 o;
#pragma unroll
    for (int i = 0; i < 4; ++i) {
      UHP q; q.u = u[i];
      o[i] = (float)q.hp.h + (float)q.hp.p * h0[i];
    }
    *(f32x4*)(out + idx) = o;
  }
}

// ---------------------------------------------------------------------------
extern "C" void kernel_launch(void* const* d_in, const int* in_sizes, int n_in,
                              void* d_out, int out_size, void* d_ws, size_t ws_size,
                              hipStream_t stream) {
  const float* inputs = (const float*)d_in[0];
  const float* mask   = (const float*)d_in[1];
  const float* W_in   = (const float*)d_in[2];
  const float* b_in   = (const float*)d_in[3];
  const float* W_f    = (const float*)d_in[4];
  const float* b_f    = (const float*)d_in[5];
  float* out = (float*)d_out;
  char* ws = (char*)d_ws;

  constexpr size_t HPSZ = (size_t)M_ * D_ * 4;                    // 32 MiB
  constexpr size_t WSZ  = (size_t)2 * 256 * 256 * 2;              // 256 KiB
  constexpr size_t SUM  = (size_t)NBLK * D_ * sizeof(float);      // 1 MiB

  unsigned int* HPb = (unsigned int*)ws;
  _Float16* Wh2 = (_Float16*)(ws + HPSZ);
  float* Ap = (float*)(ws + HPSZ + WSZ);
  float* Hp = (float*)(ws + HPSZ + WSZ + SUM);

  wconv<<<64, 256, 0, stream>>>(W_in, W_f, Wh2);
  gemm_hp<<<NBLK, 256, 0, stream>>>(inputs, Wh2, b_in, b_f, mask, HPb, Ap, Hp);
  final_k<<<NBLK, 256, 0, stream>>>(HPb, Ap, Hp, out);
}

// Round 9
// 125.228 us; speedup vs baseline: 1.5315x; 1.1237x over previous
//
#include <hip/hip_runtime.h>
#include <math.h>

// ---------------------------------------------------------------------------
// EntRNN R15b: resubmit of R15 (Round 8 never acquired a GPU).
// R14's CHUNK=32 gemm (proven: 57 -> ~40us via 4 blocks/CU) + R10's scan_mid
// reinstated (R14's fused per-block prefix walk cost ~+20us: O(NCH^2)
// redundant cross-XCD aggregate reads, 127-deep chains). final_k is pure
// streaming again (hs precomputed once by scan_mid).
// Note: ~47us of the measured total is harness fill/memset inside the timed
// path (top-5 = fillBufferAligned 42us x 256MiB) — not addressable here.
// B=8, T=4096, D=256.
// ---------------------------------------------------------------------------

typedef _Float16 f16x8 __attribute__((ext_vector_type(8)));
typedef float f32x4 __attribute__((ext_vector_type(4)));
typedef float f32x16 __attribute__((ext_vector_type(16)));
typedef unsigned int u32x4 __attribute__((ext_vector_type(4)));

constexpr int B_ = 8, T_ = 4096, D_ = 256, K_ = 256;
constexpr int M_ = B_ * T_;          // 32768 rows
constexpr int CHUNK = 32;            // rows per gemm block == scan chunk
constexpr int NCH = T_ / CHUNK;      // 128 chunks per sequence
constexpr int NBLK = M_ / CHUNK;     // 1024 gemm blocks
constexpr int SLICE_EL = 8192;       // W slice stride in f16 elements

struct alignas(4) XF { _Float16 x, f; };
struct alignas(4) HP2 { _Float16 h, p; };
union UHP { unsigned int u; HP2 hp; XF xf; };

__device__ __forceinline__ float fexp2(float a) { return __builtin_amdgcn_exp2f(a); }
__device__ __forceinline__ float frcp(float a) { return __builtin_amdgcn_rcpf(a); }
constexpr float L2E = 1.4426950408889634f;

__device__ __forceinline__ float fast_sigmoid(float z) {
  return frcp(1.f + fexp2(-z * L2E));
}
__device__ __forceinline__ float fast_tanh(float z) {
  const float t = fexp2(-2.f * L2E * fabsf(z));
  return copysignf((1.f - t) * frcp(1.f + t), z);
}

// ---- K0: repack W fp32 -> f16. Chunk id t = kk2*1024 + (mat*2+kc)*256 + n,
// chunk = W[n][kk2*16 + kc*8 .. +8). 16384 chunks of 8 f16.
__global__ __launch_bounds__(256) void wconv(const float* __restrict__ Win,
                                             const float* __restrict__ Wf,
                                             _Float16* __restrict__ Wh2) {
  const int t = blockIdx.x * 256 + threadIdx.x;
  const int n = t & 255;
  const int kc = (t >> 8) & 1;
  const int mat = (t >> 9) & 1;
  const int kk2 = t >> 10;
  const float* s = (mat ? Wf : Win) + (size_t)n * K_ + kk2 * 16 + kc * 8;
  f32x4 a = *(const f32x4*)s;
  f32x4 b = *(const f32x4*)(s + 4);
  f16x8 o;
  o[0] = (_Float16)a[0]; o[1] = (_Float16)a[1];
  o[2] = (_Float16)a[2]; o[3] = (_Float16)a[3];
  o[4] = (_Float16)b[0]; o[5] = (_Float16)b[1];
  o[6] = (_Float16)b[2]; o[7] = (_Float16)b[3];
  *(f16x8*)(Wh2 + (size_t)t * 8) = o;
}

// ---- K1: GEMM (32-row tile) + activations + local scan -> HP --------------
// 1024 blocks x 256 thr, 32 KiB LDS -> 4 blocks/CU (VGPR-capped via
// launch_bounds(256,4)). Wave w owns cols [w*64, w*64+64) of BOTH matrices.
__global__ __launch_bounds__(256, 4) void gemm_hp(
    const float* __restrict__ A, const _Float16* __restrict__ Wh2,
    const float* __restrict__ bin, const float* __restrict__ bfv,
    const float* __restrict__ mask, unsigned int* __restrict__ HPout,
    float* __restrict__ Ap, float* __restrict__ Hp) {
  __shared__ __align__(16) char smem[32768];
  char* ldsA = smem;            // 16 KiB: [m(32)][swz(32)] 16B, swz = kcg^m
  char* ldsW = smem + 16384;    // 16 KiB slice: [(mat*2+kc)*256 + n] 16B
  // epilogue: smem[0:32768) = 32 rows x 256 cols of XF/HP2 (4B each)

  const int tid = threadIdx.x;
  const int w = tid >> 6, lane = tid & 63;
  const int nl = lane & 31, kh = lane >> 5;
  const int g = blockIdx.x;
  const int row0 = g * CHUNK;

  f32x16 acc[2][2];
#pragma unroll
  for (int mat = 0; mat < 2; ++mat)
#pragma unroll
    for (int nt = 0; nt < 2; ++nt) acc[mat][nt] = (f32x16)(0.f);

  // ---- stage ALL of A (32 x 256) fp32->f16, xor-swizzled ----
  {
    const int am = tid >> 3;                 // row 0..31 (8 thr/row)
    const int ak4 = (tid & 7) * 4;           // 16B-chunk base within row
    const float* agp = A + (size_t)(row0 + am) * K_ + (tid & 7) * 32;
#pragma unroll
    for (int j = 0; j < 4; ++j) {
      const int kcg = ak4 + j;
      f32x4 lo = *(const f32x4*)(agp + j * 8);
      f32x4 hi = *(const f32x4*)(agp + j * 8 + 4);
      f16x8 t;
      t[0] = (_Float16)lo[0]; t[1] = (_Float16)lo[1];
      t[2] = (_Float16)lo[2]; t[3] = (_Float16)lo[3];
      t[4] = (_Float16)hi[0]; t[5] = (_Float16)hi[1];
      t[6] = (_Float16)hi[2]; t[7] = (_Float16)hi[3];
      *(f16x8*)(ldsA + am * 512 + ((kcg ^ am) << 4)) = t;
    }
  }

  // ---- prologue: W slice kk2=0 into regs (4 x b128) ----
  f16x8 wreg[4];
#pragma unroll
  for (int j = 0; j < 4; ++j)
    wreg[j] = *(const f16x8*)(Wh2 + (size_t)(j * 256 + tid) * 8);
  __syncthreads();

  // ---- K-loop: 16 slices of K=16 (reg-prefetch double buffer) ----
  for (int kk2 = 0; kk2 < 16; ++kk2) {
#pragma unroll
    for (int j = 0; j < 4; ++j)
      *(f16x8*)(ldsW + (size_t)(j * 256 + tid) * 16) = wreg[j];
    if (kk2 < 15) {
#pragma unroll
      for (int j = 0; j < 4; ++j)
        wreg[j] = *(const f16x8*)(Wh2 + (size_t)(kk2 + 1) * SLICE_EL +
                                  (size_t)(j * 256 + tid) * 8);
    }
    __syncthreads();
    f16x8 afr;
    {
      const int kcg = kk2 * 2 + kh;
      afr = *(const f16x8*)(ldsA + nl * 512 + ((kcg ^ nl) << 4));
    }
#pragma unroll
    for (int mat = 0; mat < 2; ++mat)
#pragma unroll
      for (int nt = 0; nt < 2; ++nt) {
        const int n = w * 64 + nt * 32 + nl;
        f16x8 bfr = *(const f16x8*)(ldsW + (size_t)((mat * 2 + kh) * 256 + n) * 16);
        acc[mat][nt] = __builtin_amdgcn_mfma_f32_32x32x16_f16(
            afr, bfr, acc[mat][nt], 0, 0, 0);
      }
    __syncthreads();
  }

  // ---- epilogue: activations for all 32 rows into 32 KiB LDS ----
  float bx[2], bf[2];
#pragma unroll
  for (int nt = 0; nt < 2; ++nt) {
    const int col = w * 64 + nt * 32 + nl;
    bx[nt] = bin[col];
    bf[nt] = bfv[col];
  }
  float madd[16];
#pragma unroll
  for (int reg = 0; reg < 16; ++reg) {
    const int rl = (reg & 3) + 8 * (reg >> 2) + 4 * kh;   // 0..31
    madd[reg] = 10000.f * mask[row0 + rl];
  }

#pragma unroll
  for (int nt = 0; nt < 2; ++nt) {
    const int col = w * 64 + nt * 32 + nl;
#pragma unroll
    for (int reg = 0; reg < 16; ++reg) {
      const int rloc = (reg & 3) + 8 * (reg >> 2) + 4 * kh;  // 0..31
      const float zx = acc[0][nt][reg] + bx[nt];
      const float zf = acc[1][nt][reg] + bf[nt] + madd[reg];
      XF v;
      v.x = (_Float16)fast_tanh(zx);
      v.f = (_Float16)fast_sigmoid(zf);
      *(XF*)(smem + ((size_t)rloc * D_ + col) * 4) = v;
    }
  }
  __syncthreads();

  // ---- local scan: 32 timesteps in place (XF -> HP2) ----
  const int d = tid;
  float hrun = 0.f, Prun = 1.f;
#pragma unroll 8
  for (int t = 0; t < 32; ++t) {
    char* slot = smem + ((size_t)t * D_ + d) * 4;
    const XF v = *(const XF*)slot;
    const float f = (float)v.f;
    const float a = 1.f - f;
    hrun = f * (float)v.x + a * hrun;
    Prun *= a;
    HP2 o;
    o.h = (_Float16)hrun;
    o.p = (_Float16)Prun;
    *(HP2*)slot = o;
  }
  __syncthreads();

  // ---- bulk-coalesced b128 store of the 32-row HP stage (32 KiB) ----
#pragma unroll
  for (int j = 0; j < 8; ++j) {
    const int c = j * 256 + tid;              // 16B chunk id in [0,2048)
    u32x4 vv = *(const u32x4*)(smem + (size_t)c * 16);
    *(u32x4*)(HPout + (size_t)g * 8192 + (size_t)c * 4) = vv;
  }

  Ap[(size_t)g * D_ + d] = Prun;
  Hp[(size_t)g * D_ + d] = hrun;
}

// ---- K2: chunk carries, computed ONCE. 8 blocks x 256 thr ----------------
__global__ __launch_bounds__(256) void scan_mid(const float* __restrict__ Ap,
                                                const float* __restrict__ Hp,
                                                float* __restrict__ hs) {
  const int b = blockIdx.x, d = threadIdx.x;
  float h = 0.f;
#pragma unroll 8
  for (int c = 0; c < NCH; ++c) {
    const size_t i = ((size_t)(b * NCH + c)) * D_ + d;
    hs[i] = h;                         // carry INTO chunk c
    h = Hp[i] + Ap[i] * h;
  }
}

// ---- K3: h = h_local + P * h_start, pure streaming ------------------------
__global__ __launch_bounds__(256) void final_k(const unsigned int* __restrict__ HP,
                                               const float* __restrict__ hs,
                                               float* __restrict__ out) {
  const int g = blockIdx.x;
  const int wv = threadIdx.x >> 6;
  const int d0 = (threadIdx.x & 63) * 4;
  const f32x4 h0 = *(const f32x4*)(hs + (size_t)g * D_ + d0);
#pragma unroll 4
  for (int tt = 0; tt < 8; ++tt) {
    const int t = wv * 8 + tt;
    const size_t idx = ((size_t)g * CHUNK + t) * D_ + d0;
    u32x4 u = *(const u32x4*)(HP + idx);
    f32x4 o;
#pragma unroll
    for (int i = 0; i < 4; ++i) {
      UHP q; q.u = u[i];
      o[i] = (float)q.hp.h + (float)q.hp.p * h0[i];
    }
    *(f32x4*)(out + idx) = o;
  }
}

// ---------------------------------------------------------------------------
extern "C" void kernel_launch(void* const* d_in, const int* in_sizes, int n_in,
                              void* d_out, int out_size, void* d_ws, size_t ws_size,
                              hipStream_t stream) {
  const float* inputs = (const float*)d_in[0];
  const float* mask   = (const float*)d_in[1];
  const float* W_in   = (const float*)d_in[2];
  const float* b_in   = (const float*)d_in[3];
  const float* W_f    = (const float*)d_in[4];
  const float* b_f    = (const float*)d_in[5];
  float* out = (float*)d_out;
  char* ws = (char*)d_ws;

  constexpr size_t HPSZ = (size_t)M_ * D_ * 4;                    // 32 MiB
  constexpr size_t WSZ  = (size_t)2 * 256 * 256 * 2;              // 256 KiB
  constexpr size_t SUM  = (size_t)NBLK * D_ * sizeof(float);      // 1 MiB

  unsigned int* HPb = (unsigned int*)ws;
  _Float16* Wh2 = (_Float16*)(ws + HPSZ);
  float* Ap = (float*)(ws + HPSZ + WSZ);
  float* Hp = (float*)(ws + HPSZ + WSZ + SUM);
  float* hs = (float*)(ws + HPSZ + WSZ + 2 * SUM);

  wconv<<<64, 256, 0, stream>>>(W_in, W_f, Wh2);
  gemm_hp<<<NBLK, 256, 0, stream>>>(inputs, Wh2, b_in, b_f, mask, HPb, Ap, Hp);
  scan_mid<<<B_, 256, 0, stream>>>(Ap, Hp, hs);
  final_k<<<NBLK, 256, 0, stream>>>(HPb, hs, out);
}